// Round 1
// baseline (2085.219 us; speedup 1.0000x reference)
//
#include <hip/hip_runtime.h>
#include <math.h>

namespace {

constexpr int kC = 512;
constexpr int kH = 512;
constexpr int kN = 64;
constexpr int kMat = kC * kH;                    // 262144
constexpr float kInvS = 0.04419417382415922f;    // 1/sqrt(512)

enum { SRC_RAW = 0, SRC_X, SRC_T2, SRC_T3, SRC_T4, SRC_T5, SRC_T7, SRC_T11 };

__device__ __forceinline__ float4 ld4(const float* p) {
  return *reinterpret_cast<const float4*>(p);
}

// elem4<SRC>: returns elements [r][s..s+3] of the chosen (virtual) tensor.
// For derived tensors r is the c-index, s is the h-index.
//   T2  = roll(x, 2, axis=c)
//   T3  = t1[h] + T2
//   T4  = x * T3
//   T5  = relu(x)
//   T7  = p7 * T5
//   T11 = min(T4, x)
template <int SRC>
__device__ __forceinline__ float4 elem4(const float* __restrict__ raw,
                                        const float* __restrict__ x,
                                        const float* __restrict__ t1,
                                        const float* __restrict__ p7,
                                        int n, int r, int s) {
  const int nb = n * kMat;
  if constexpr (SRC == SRC_RAW) {
    return ld4(raw + nb + r * kH + s);
  } else if constexpr (SRC == SRC_X) {
    return ld4(x + nb + r * kH + s);
  } else if constexpr (SRC == SRC_T5) {
    float4 v = ld4(x + nb + r * kH + s);
    return make_float4(fmaxf(v.x, 0.f), fmaxf(v.y, 0.f),
                       fmaxf(v.z, 0.f), fmaxf(v.w, 0.f));
  } else if constexpr (SRC == SRC_T7) {
    float4 v = ld4(x + nb + r * kH + s);
    float4 p = ld4(p7 + r * kH + s);
    return make_float4(p.x * fmaxf(v.x, 0.f), p.y * fmaxf(v.y, 0.f),
                       p.z * fmaxf(v.z, 0.f), p.w * fmaxf(v.w, 0.f));
  } else {
    const int rr = (r + kC - 2) & (kC - 1);      // rolled c-index
    float4 xr = ld4(x + nb + rr * kH + s);
    if constexpr (SRC == SRC_T2) return xr;
    float4 tv = ld4(t1 + n * kH + s);
    float4 t3 = make_float4(tv.x + xr.x, tv.y + xr.y, tv.z + xr.z, tv.w + xr.w);
    if constexpr (SRC == SRC_T3) return t3;
    float4 xv = ld4(x + nb + r * kH + s);
    float4 t4 = make_float4(xv.x * t3.x, xv.y * t3.y, xv.z * t3.z, xv.w * t3.w);
    if constexpr (SRC == SRC_T4) return t4;
    return make_float4(fminf(t4.x, xv.x), fminf(t4.y, xv.y),
                       fminf(t4.z, xv.z), fminf(t4.w, xv.w));  // T11
  }
}

// C[i,j] = alpha * sum_k opA(i,k) * opB(k,j), all matrices 512x512 per batch.
//   AT=0: opA(i,k) = elemA(r=i, s=k)    AT=1: opA(i,k) = elemA(r=k, s=i)
//   BT=0: opB(k,j) = elemB(r=k, s=j)    BT=1: opB(k,j) = elemB(r=j, s=k)
template <int ASRC, int AT, int BSRC, int BT>
__global__ __launch_bounds__(256) void gemm_kernel(
    const float* __restrict__ Araw, const float* __restrict__ Braw,
    const float* __restrict__ x, const float* __restrict__ t1,
    const float* __restrict__ p7, float* __restrict__ C, float alpha) {
  constexpr int BM = 128, BN = 128, BK = 16;
  __shared__ float As[BK][BM + 4];
  __shared__ float Bs[BK][BN + 4];
  const int n = blockIdx.z;
  const int i0 = blockIdx.y * BM;
  const int j0 = blockIdx.x * BN;
  const int tid = threadIdx.x;
  const int tx = tid & 15;
  const int ty = tid >> 4;

  float acc[8][8];
#pragma unroll
  for (int r = 0; r < 8; ++r)
#pragma unroll
    for (int c = 0; c < 8; ++c) acc[r][c] = 0.f;

  for (int k0 = 0; k0 < kC; k0 += BK) {
#pragma unroll
    for (int t = 0; t < 2; ++t) {
      int e = tid + t * 256;                     // 512 float4s per tile
      if constexpr (AT) {
        int k = e >> 5;                          // BK rows of BM contiguous
        int i4 = (e & 31) << 2;
        float4 v = elem4<ASRC>(Araw, x, t1, p7, n, k0 + k, i0 + i4);
        *reinterpret_cast<float4*>(&As[k][i4]) = v;
      } else {
        int i = e >> 2;                          // BM rows of BK contiguous
        int k4 = (e & 3) << 2;
        float4 v = elem4<ASRC>(Araw, x, t1, p7, n, i0 + i, k0 + k4);
        As[k4 + 0][i] = v.x; As[k4 + 1][i] = v.y;
        As[k4 + 2][i] = v.z; As[k4 + 3][i] = v.w;
      }
    }
#pragma unroll
    for (int t = 0; t < 2; ++t) {
      int e = tid + t * 256;
      if constexpr (!BT) {
        int k = e >> 5;
        int j4 = (e & 31) << 2;
        float4 v = elem4<BSRC>(Braw, x, t1, p7, n, k0 + k, j0 + j4);
        *reinterpret_cast<float4*>(&Bs[k][j4]) = v;
      } else {
        int j = e >> 2;
        int k4 = (e & 3) << 2;
        float4 v = elem4<BSRC>(Braw, x, t1, p7, n, j0 + j, k0 + k4);
        Bs[k4 + 0][j] = v.x; Bs[k4 + 1][j] = v.y;
        Bs[k4 + 2][j] = v.z; Bs[k4 + 3][j] = v.w;
      }
    }
    __syncthreads();
#pragma unroll
    for (int k = 0; k < BK; ++k) {
      float a[8], b[8];
      *reinterpret_cast<float4*>(&a[0]) =
          *reinterpret_cast<const float4*>(&As[k][ty * 8]);
      *reinterpret_cast<float4*>(&a[4]) =
          *reinterpret_cast<const float4*>(&As[k][ty * 8 + 4]);
      *reinterpret_cast<float4*>(&b[0]) =
          *reinterpret_cast<const float4*>(&Bs[k][tx * 8]);
      *reinterpret_cast<float4*>(&b[4]) =
          *reinterpret_cast<const float4*>(&Bs[k][tx * 8 + 4]);
#pragma unroll
      for (int r = 0; r < 8; ++r)
#pragma unroll
        for (int c = 0; c < 8; ++c) acc[r][c] = fmaf(a[r], b[c], acc[r][c]);
    }
    __syncthreads();
  }

  const int nb = n * kMat;
#pragma unroll
  for (int r = 0; r < 8; ++r) {
    int row = i0 + ty * 8 + r;
    float* cp = C + nb + row * kH + j0 + tx * 8;
    float4 o0 = make_float4(acc[r][0] * alpha, acc[r][1] * alpha,
                            acc[r][2] * alpha, acc[r][3] * alpha);
    float4 o1 = make_float4(acc[r][4] * alpha, acc[r][5] * alpha,
                            acc[r][6] * alpha, acc[r][7] * alpha);
    *reinterpret_cast<float4*>(cp) = o0;
    *reinterpret_cast<float4*>(cp + 4) = o1;
  }
}

// t1[n,h] = sum_c x[n,c,h] * w[c]
__global__ __launch_bounds__(256) void t1_kernel(const float* __restrict__ x,
                                                 const float* __restrict__ w,
                                                 float* __restrict__ t1) {
  int idx = blockIdx.x * 256 + threadIdx.x;    // n*kH + h
  int n = idx >> 9;
  int h = idx & (kH - 1);
  const float* xp = x + n * kMat + h;
  float s = 0.f;
#pragma unroll 8
  for (int c = 0; c < kC; ++c) s = fmaf(xp[c * kH], w[c], s);
  t1[idx] = s;
}

// in-place stable softmax over rows of 512 floats; one block per row
__global__ __launch_bounds__(256) void softmax_kernel(float* __restrict__ buf) {
  __shared__ float red[8];
  float* p = buf + (size_t)blockIdx.x * kH;
  int t = threadIdx.x;
  float2 v = reinterpret_cast<float2*>(p)[t];
  float m = fmaxf(v.x, v.y);
#pragma unroll
  for (int o = 32; o; o >>= 1) m = fmaxf(m, __shfl_xor(m, o));
  if ((t & 63) == 0) red[t >> 6] = m;
  __syncthreads();
  m = fmaxf(fmaxf(red[0], red[1]), fmaxf(red[2], red[3]));
  float e0 = expf(v.x - m), e1 = expf(v.y - m);
  float s = e0 + e1;
#pragma unroll
  for (int o = 32; o; o >>= 1) s += __shfl_xor(s, o);
  __syncthreads();
  if ((t & 63) == 0) red[4 + (t >> 6)] = s;
  __syncthreads();
  s = red[4] + red[5] + red[6] + red[7];
  float inv = 1.f / s;
  reinterpret_cast<float2*>(p)[t] = make_float2(e0 * inv, e1 * inv);
}

}  // namespace

extern "C" void kernel_launch(void* const* d_in, const int* in_sizes, int n_in,
                              void* d_out, int out_size, void* d_ws,
                              size_t ws_size, hipStream_t stream) {
  (void)in_sizes; (void)n_in; (void)out_size;
  const float* x  = (const float*)d_in[0];
  const float* w  = (const float*)d_in[1];   // p1_w (C,1)
  const float* p7 = (const float*)d_in[2];   // p7_w (1,C,H)
  float* out = (float*)d_out;

  const size_t BUF = (size_t)kN * kMat;      // floats per (n,512,512) tensor
  const size_t need = (4 * BUF + (size_t)kN * kH) * sizeof(float);
  float* ws = (float*)d_ws;
  if (ws_size < need) {
    // Safety net: allocated on the first (uncaptured) call only; during graph
    // capture the pointer is already set so no HIP alloc API is invoked.
    static float* g_extra = nullptr;
    if (!g_extra) (void)hipMalloc((void**)&g_extra, need);
    ws = g_extra;
  }
  float* b0 = ws;
  float* b1 = b0 + BUF;
  float* b2 = b1 + BUF;
  float* b3 = b2 + BUF;
  float* t1 = b3 + BUF;

  dim3 gg(4, 4, kN);
  dim3 bb(256);
  const int rows = kN * kH;                  // 32768

  t1_kernel<<<rows / 256, bb, 0, stream>>>(x, w, t1);

  // t9 = t5 @ t4^T * invS                                  -> b0
  gemm_kernel<SRC_T5, 0, SRC_T4, 1><<<gg, bb, 0, stream>>>(nullptr, nullptr, x, t1, p7, b0, kInvS);
  // t10 = softmax(t7 @ t3^T * invS)                        -> b1
  gemm_kernel<SRC_T7, 0, SRC_T3, 1><<<gg, bb, 0, stream>>>(nullptr, nullptr, x, t1, p7, b1, kInvS);
  softmax_kernel<<<rows, bb, 0, stream>>>(b1);
  // t14 = softmax(S14), S14[i,j] = sum_k t9[k,i]*t10[j,k] * invS -> b2
  gemm_kernel<SRC_RAW, 1, SRC_RAW, 1><<<gg, bb, 0, stream>>>(b0, b1, x, t1, p7, b2, kInvS);
  softmax_kernel<<<rows, bb, 0, stream>>>(b2);
  // t12[i,h] = sum_d t9[d,i]*t7[d,h] * invS                -> b1 (t10 dead)
  gemm_kernel<SRC_RAW, 1, SRC_T7, 0><<<gg, bb, 0, stream>>>(b0, nullptr, x, t1, p7, b1, kInvS);
  // t16[h,j] = sum_k t12[k,h]*t14[j,k] * invS              -> b0 (t9 dead)
  gemm_kernel<SRC_RAW, 1, SRC_RAW, 1><<<gg, bb, 0, stream>>>(b1, b2, x, t1, p7, b0, kInvS);
  // t13[h,g] = sum_c t11[c,h]*t2[c,g] * invS               -> b1 (t12 dead)
  gemm_kernel<SRC_T11, 1, SRC_T2, 0><<<gg, bb, 0, stream>>>(nullptr, nullptr, x, t1, p7, b1, kInvS);
  // t8 = softmax(t5^T @ x * invS)                          -> b2 (t14 dead)
  gemm_kernel<SRC_T5, 1, SRC_X, 0><<<gg, bb, 0, stream>>>(nullptr, nullptr, x, t1, p7, b2, kInvS);
  softmax_kernel<<<rows, bb, 0, stream>>>(b2);
  // t15 = softmax(t13 @ t8 * invS)                         -> b3
  gemm_kernel<SRC_RAW, 0, SRC_RAW, 0><<<gg, bb, 0, stream>>>(b1, b2, x, t1, p7, b3, kInvS);
  softmax_kernel<<<rows, bb, 0, stream>>>(b3);
  // t17[c,j] = sum_k t16[k,c]*t15[k,j] * invS              -> out
  gemm_kernel<SRC_RAW, 1, SRC_RAW, 0><<<gg, bb, 0, stream>>>(b0, b3, x, t1, p7, out, kInvS);
}

// Round 3
// 1347.555 us; speedup vs baseline: 1.5474x; 1.5474x over previous
//
#include <hip/hip_runtime.h>
#include <math.h>

namespace {

constexpr int kC = 512;
constexpr int kH = 512;
constexpr int kN = 64;
constexpr int kMat = kC * kH;                    // 262144
constexpr float kInvS = 0.04419417382415922f;    // 1/sqrt(512)

enum { SRC_RAW = 0, SRC_X, SRC_T2, SRC_T3, SRC_T4, SRC_T5, SRC_T7, SRC_T11 };

using bf16x8 = __attribute__((ext_vector_type(8))) __bf16;
using f32x4  = __attribute__((ext_vector_type(4))) float;

__device__ __forceinline__ float4 ld4(const float* p) {
  return *reinterpret_cast<const float4*>(p);
}

// elem4<SRC>: elements [r][s..s+3] of the chosen (virtual) tensor.
// For derived tensors r is the c-index, s is the h-index.
template <int SRC>
__device__ __forceinline__ float4 elem4(const float* __restrict__ raw,
                                        const float* __restrict__ x,
                                        const float* __restrict__ t1,
                                        const float* __restrict__ p7,
                                        int n, int r, int s) {
  const int nb = n * kMat;
  if constexpr (SRC == SRC_RAW) {
    return ld4(raw + nb + r * kH + s);
  } else if constexpr (SRC == SRC_X) {
    return ld4(x + nb + r * kH + s);
  } else if constexpr (SRC == SRC_T5) {
    float4 v = ld4(x + nb + r * kH + s);
    return make_float4(fmaxf(v.x, 0.f), fmaxf(v.y, 0.f),
                       fmaxf(v.z, 0.f), fmaxf(v.w, 0.f));
  } else if constexpr (SRC == SRC_T7) {
    float4 v = ld4(x + nb + r * kH + s);
    float4 p = ld4(p7 + r * kH + s);
    return make_float4(p.x * fmaxf(v.x, 0.f), p.y * fmaxf(v.y, 0.f),
                       p.z * fmaxf(v.z, 0.f), p.w * fmaxf(v.w, 0.f));
  } else {
    const int rr = (r + kC - 2) & (kC - 1);      // rolled c-index
    float4 xr = ld4(x + nb + rr * kH + s);
    if constexpr (SRC == SRC_T2) return xr;
    float4 tv = ld4(t1 + n * kH + s);
    float4 t3 = make_float4(tv.x + xr.x, tv.y + xr.y, tv.z + xr.z, tv.w + xr.w);
    if constexpr (SRC == SRC_T3) return t3;
    float4 xv = ld4(x + nb + r * kH + s);
    float4 t4 = make_float4(xv.x * t3.x, xv.y * t3.y, xv.z * t3.z, xv.w * t3.w);
    if constexpr (SRC == SRC_T4) return t4;
    return make_float4(fminf(t4.x, xv.x), fminf(t4.y, xv.y),
                       fminf(t4.z, xv.z), fminf(t4.w, xv.w));  // T11
  }
}

// packed f32 pair -> bf16 pair (hw round)
__device__ __forceinline__ unsigned cvtpk(float lo, float hi) {
  unsigned r;
  asm("v_cvt_pk_bf16_f32 %0, %1, %2" : "=v"(r) : "v"(lo), "v"(hi));
  return r;
}

// exact 3-plane split of two f32 values (pair along K):
// q0/q1/q2 are packed bf16 pairs for planes 0/1/2; a = a0+a1+a2 (near-)exactly.
__device__ __forceinline__ void split2(float a, float b, unsigned& q0,
                                       unsigned& q1, unsigned& q2) {
  q0 = cvtpk(a, b);
  float a0 = __builtin_bit_cast(float, q0 << 16);
  float b0 = __builtin_bit_cast(float, q0 & 0xFFFF0000u);
  float ra = a - a0, rb = b - b0;
  q1 = cvtpk(ra, rb);
  float a1 = __builtin_bit_cast(float, q1 << 16);
  float b1 = __builtin_bit_cast(float, q1 & 0xFFFF0000u);
  q2 = cvtpk(ra - a1, rb - b1);
}

// LDS geometry (ushort units): plane [128 rows][40], row stride 40 (80 B,
// +8 bf16 pad -> fragment ds_read_b128 lands 2-way per bank = free).
constexpr int kRowS = 40;
constexpr int kPlane = 128 * kRowS;              // 5120 ushorts
constexpr int kMatS = 3 * kPlane;                // per-matrix (3 planes)

__device__ __forceinline__ void store3(unsigned short* dst, int off,
                                       unsigned p0a, unsigned p0b,
                                       unsigned p1a, unsigned p1b,
                                       unsigned p2a, unsigned p2b) {
  *reinterpret_cast<uint2*>(dst + off)              = make_uint2(p0a, p0b);
  *reinterpret_cast<uint2*>(dst + kPlane + off)     = make_uint2(p1a, p1b);
  *reinterpret_cast<uint2*>(dst + 2 * kPlane + off) = make_uint2(p2a, p2b);
}

// Stage one 128x32 operand tile (as [row][k], k contiguous) into 3 bf16 planes.
// TRANS=0: dest[row][k] = elem(r = r0+row, s = k0+k)   (source k-contiguous)
// TRANS=1: dest[row][k] = elem(r = k0+k,  s = r0+row)  (source row-contiguous)
template <int SRC, bool TRANS>
__device__ __forceinline__ void stage_tile(unsigned short* dst,
                                           const float* __restrict__ raw,
                                           const float* __restrict__ x,
                                           const float* __restrict__ t1,
                                           const float* __restrict__ p7,
                                           int n, int r0, int k0, int tid) {
  if constexpr (!TRANS) {
#pragma unroll
    for (int i = 0; i < 4; ++i) {
      int e = tid + i * 256;                     // 0..1023
      int row = e >> 3;
      int k4 = (e & 7) << 2;
      float4 v = elem4<SRC>(raw, x, t1, p7, n, r0 + row, k0 + k4);
      unsigned p0a, p1a, p2a, p0b, p1b, p2b;
      split2(v.x, v.y, p0a, p1a, p2a);
      split2(v.z, v.w, p0b, p1b, p2b);
      store3(dst, row * kRowS + k4, p0a, p0b, p1a, p1b, p2a, p2b);
    }
  } else {
    int kb = tid >> 5;                           // 0..7
    int mb = tid & 31;                           // 0..31
    float4 v[4];
#pragma unroll
    for (int j = 0; j < 4; ++j)
      v[j] = elem4<SRC>(raw, x, t1, p7, n, k0 + kb * 4 + j, r0 + mb * 4);
    const float* vf = reinterpret_cast<const float*>(v);
#pragma unroll
    for (int i = 0; i < 4; ++i) {                // 4x4 in-register transpose
      unsigned p0a, p1a, p2a, p0b, p1b, p2b;
      split2(vf[0 * 4 + i], vf[1 * 4 + i], p0a, p1a, p2a);
      split2(vf[2 * 4 + i], vf[3 * 4 + i], p0b, p1b, p2b);
      store3(dst, (mb * 4 + i) * kRowS + kb * 4, p0a, p0b, p1a, p1b, p2a, p2b);
    }
  }
}

// C[i,j] = alpha * sum_k opA(i,k)*opB(k,j); 512x512 per batch; bf16x3-split
// MFMA (6 products: a0b0,a0b1,a1b0,a1b1,a0b2,a2b0) with f32 accumulate.
template <int ASRC, int AT, int BSRC, int BT>
__global__ __launch_bounds__(256, 2) void gemm_kernel(
    const float* __restrict__ Araw, const float* __restrict__ Braw,
    const float* __restrict__ x, const float* __restrict__ t1,
    const float* __restrict__ p7, float* __restrict__ C, float alpha) {
  __shared__ unsigned short smem[2 * kMatS];     // 61440 B
  const int n = blockIdx.z;
  const int i0 = blockIdx.y * 128;
  const int j0 = blockIdx.x * 128;
  const int tid = threadIdx.x;
  const int lane = tid & 63;
  const int wid = tid >> 6;
  const int wr = wid >> 1, wc = wid & 1;         // wave -> 64x64 sub-tile

  f32x4 acc[4][4];
#pragma unroll
  for (int a = 0; a < 4; ++a)
#pragma unroll
    for (int b = 0; b < 4; ++b) acc[a][b] = (f32x4)0.f;

  const int frow = lane & 15;                    // fragment row/col within 16
  const int kq = (lane >> 4) * 8;                // k-offset (ushort units)

  for (int k0 = 0; k0 < kC; k0 += 32) {
    __syncthreads();
    stage_tile<ASRC, AT == 1>(smem, Araw, x, t1, p7, n, i0, k0, tid);
    stage_tile<BSRC, BT == 0>(smem + kMatS, Braw, x, t1, p7, n, j0, k0, tid);
    __syncthreads();

    bf16x8 B0[4], B1[4], B2[4];
#pragma unroll
    for (int nj = 0; nj < 4; ++nj) {
      int off = kMatS + (wc * 64 + nj * 16 + frow) * kRowS + kq;
      B0[nj] = *reinterpret_cast<const bf16x8*>(smem + off);
      B1[nj] = *reinterpret_cast<const bf16x8*>(smem + kPlane + off);
      B2[nj] = *reinterpret_cast<const bf16x8*>(smem + 2 * kPlane + off);
    }
#pragma unroll
    for (int mi = 0; mi < 4; ++mi) {
      int off = (wr * 64 + mi * 16 + frow) * kRowS + kq;
      bf16x8 A0 = *reinterpret_cast<const bf16x8*>(smem + off);
      bf16x8 A1 = *reinterpret_cast<const bf16x8*>(smem + kPlane + off);
      bf16x8 A2 = *reinterpret_cast<const bf16x8*>(smem + 2 * kPlane + off);
#pragma unroll
      for (int nj = 0; nj < 4; ++nj) {
        f32x4 c = acc[mi][nj];
        c = __builtin_amdgcn_mfma_f32_16x16x32_bf16(A1, B1[nj], c, 0, 0, 0);
        c = __builtin_amdgcn_mfma_f32_16x16x32_bf16(A0, B2[nj], c, 0, 0, 0);
        c = __builtin_amdgcn_mfma_f32_16x16x32_bf16(A2, B0[nj], c, 0, 0, 0);
        c = __builtin_amdgcn_mfma_f32_16x16x32_bf16(A0, B1[nj], c, 0, 0, 0);
        c = __builtin_amdgcn_mfma_f32_16x16x32_bf16(A1, B0[nj], c, 0, 0, 0);
        c = __builtin_amdgcn_mfma_f32_16x16x32_bf16(A0, B0[nj], c, 0, 0, 0);
        acc[mi][nj] = c;
      }
    }
  }

  // epilogue: C/D layout col=lane&15, row=(lane>>4)*4+reg (m89-verified)
  const int nb = n * kMat;
  const int rbase = (lane >> 4) * 4;
#pragma unroll
  for (int mi = 0; mi < 4; ++mi) {
#pragma unroll
    for (int nj = 0; nj < 4; ++nj) {
      int row0 = i0 + wr * 64 + mi * 16 + rbase;
      int col = j0 + wc * 64 + nj * 16 + frow;
      float* cp = C + nb + row0 * kH + col;
#pragma unroll
      for (int r = 0; r < 4; ++r) cp[r * kH] = acc[mi][nj][r] * alpha;
    }
  }
}

// t1[n,h] = sum_c x[n,c,h] * w[c]
__global__ __launch_bounds__(256) void t1_kernel(const float* __restrict__ x,
                                                 const float* __restrict__ w,
                                                 float* __restrict__ t1) {
  int idx = blockIdx.x * 256 + threadIdx.x;      // n*kH + h
  int n = idx >> 9;
  const float* xp = x + n * kMat + (idx & (kH - 1));
  float s = 0.f;
#pragma unroll 8
  for (int c = 0; c < kC; ++c) s = fmaf(xp[c * kH], w[c], s);
  t1[idx] = s;
}

// in-place stable softmax over rows of 512 floats; one block per row
__global__ __launch_bounds__(256) void softmax_kernel(float* __restrict__ buf) {
  __shared__ float red[8];
  float* p = buf + (size_t)blockIdx.x * kH;
  int t = threadIdx.x;
  float2 v = reinterpret_cast<float2*>(p)[t];
  float m = fmaxf(v.x, v.y);
#pragma unroll
  for (int o = 32; o; o >>= 1) m = fmaxf(m, __shfl_xor(m, o));
  if ((t & 63) == 0) red[t >> 6] = m;
  __syncthreads();
  m = fmaxf(fmaxf(red[0], red[1]), fmaxf(red[2], red[3]));
  float e0 = expf(v.x - m), e1 = expf(v.y - m);
  float s = e0 + e1;
#pragma unroll
  for (int o = 32; o; o >>= 1) s += __shfl_xor(s, o);
  __syncthreads();
  if ((t & 63) == 0) red[4 + (t >> 6)] = s;
  __syncthreads();
  s = red[4] + red[5] + red[6] + red[7];
  float inv = 1.f / s;
  reinterpret_cast<float2*>(p)[t] = make_float2(e0 * inv, e1 * inv);
}

}  // namespace

extern "C" void kernel_launch(void* const* d_in, const int* in_sizes, int n_in,
                              void* d_out, int out_size, void* d_ws,
                              size_t ws_size, hipStream_t stream) {
  (void)in_sizes; (void)n_in; (void)out_size;
  const float* x  = (const float*)d_in[0];
  const float* w  = (const float*)d_in[1];   // p1_w (C,1)
  const float* p7 = (const float*)d_in[2];   // p7_w (1,C,H)
  float* out = (float*)d_out;

  const size_t BUF = (size_t)kN * kMat;
  const size_t need = (4 * BUF + (size_t)kN * kH) * sizeof(float);
  float* ws = (float*)d_ws;
  if (ws_size < need) {
    static float* g_extra = nullptr;           // first (uncaptured) call only
    if (!g_extra) (void)hipMalloc((void**)&g_extra, need);
    ws = g_extra;
  }
  float* b0 = ws;
  float* b1 = b0 + BUF;
  float* b2 = b1 + BUF;
  float* b3 = b2 + BUF;
  float* t1 = b3 + BUF;

  dim3 gg(4, 4, kN);
  dim3 bb(256);
  const int rows = kN * kH;                    // 32768

  t1_kernel<<<rows / 256, bb, 0, stream>>>(x, w, t1);

  // t9 = t5 @ t4^T * invS                                  -> b0
  gemm_kernel<SRC_T5, 0, SRC_T4, 1><<<gg, bb, 0, stream>>>(nullptr, nullptr, x, t1, p7, b0, kInvS);
  // t10 = softmax(t7 @ t3^T * invS)                        -> b1
  gemm_kernel<SRC_T7, 0, SRC_T3, 1><<<gg, bb, 0, stream>>>(nullptr, nullptr, x, t1, p7, b1, kInvS);
  softmax_kernel<<<rows, bb, 0, stream>>>(b1);
  // t14 = softmax(S14), S14[i,j] = sum_k t9[k,i]*t10[j,k]  -> b2
  gemm_kernel<SRC_RAW, 1, SRC_RAW, 1><<<gg, bb, 0, stream>>>(b0, b1, x, t1, p7, b2, kInvS);
  softmax_kernel<<<rows, bb, 0, stream>>>(b2);
  // t12[i,h] = sum_d t9[d,i]*t7[d,h] * invS                -> b1 (t10 dead)
  gemm_kernel<SRC_RAW, 1, SRC_T7, 0><<<gg, bb, 0, stream>>>(b0, nullptr, x, t1, p7, b1, kInvS);
  // t16[h,j] = sum_k t12[k,h]*t14[j,k] * invS              -> b0 (t9 dead)
  gemm_kernel<SRC_RAW, 1, SRC_RAW, 1><<<gg, bb, 0, stream>>>(b1, b2, x, t1, p7, b0, kInvS);
  // t13[h,g] = sum_c t11[c,h]*t2[c,g] * invS               -> b1 (t12 dead)
  gemm_kernel<SRC_T11, 1, SRC_T2, 0><<<gg, bb, 0, stream>>>(nullptr, nullptr, x, t1, p7, b1, kInvS);
  // t8 = softmax(t5^T @ x * invS)                          -> b2 (t14 dead)
  gemm_kernel<SRC_T5, 1, SRC_X, 0><<<gg, bb, 0, stream>>>(nullptr, nullptr, x, t1, p7, b2, kInvS);
  softmax_kernel<<<rows, bb, 0, stream>>>(b2);
  // t15 = softmax(t13 @ t8 * invS)                         -> b3
  gemm_kernel<SRC_RAW, 0, SRC_RAW, 0><<<gg, bb, 0, stream>>>(b1, b2, x, t1, p7, b3, kInvS);
  softmax_kernel<<<rows, bb, 0, stream>>>(b3);
  // t17[c,j] = sum_k t16[k,c]*t15[k,j] * invS              -> out
  gemm_kernel<SRC_RAW, 1, SRC_RAW, 0><<<gg, bb, 0, stream>>>(b0, b3, x, t1, p7, out, kInvS);
}